// Round 2
// baseline (159.545 us; speedup 1.0000x reference)
//
#include <hip/hip_runtime.h>

#define NB   64
#define NT   256
#define NI   512
#define NO   512
#define NOBS 128
#define ETA  0.01f

typedef __attribute__((ext_vector_type(8))) short bf16x8;
typedef __attribute__((ext_vector_type(4))) float f32x4;

#define X4_COUNT  (NB*NT*NI/4)
#define WG4_COUNT (NB*NOBS*NI/4)
#define K0_TOTAL  (X4_COUNT + WG4_COUNT)

__device__ __forceinline__ unsigned short f2bf(float f) {
    unsigned int u = __float_as_uint(f);
    return (unsigned short)((u + 0x7fffu + ((u >> 16) & 1u)) >> 16); // RNE
}

// ---------------- K0: X -> bf16 ; gather obs rows of W -> bf16 ----------------
__global__ __launch_bounds__(256)
void k0_convert(const float* __restrict__ X, const float* __restrict__ Wi,
                const int* __restrict__ obs,
                unsigned short* __restrict__ Xb, unsigned short* __restrict__ Wg)
{
    int idx = blockIdx.x * 256 + threadIdx.x;
    const int stride = gridDim.x * 256;
    for (; idx < K0_TOTAL; idx += stride) {
        float4 v; ushort4* dst;
        if (idx < X4_COUNT) {
            v = ((const float4*)X)[idx];
            dst = (ushort4*)Xb + idx;
        } else {
            int g = idx - X4_COUNT;
            int row = g >> 7, pos = g & 127;
            int b = row >> 7, j = row & 127;
            v = ((const float4*)(Wi + ((size_t)b * NO + obs[j]) * NI))[pos];
            dst = (ushort4*)Wg + ((size_t)row * 128 + pos);
        }
        *dst = make_ushort4(f2bf(v.x), f2bf(v.y), f2bf(v.z), f2bf(v.w));
    }
}

// ---------------- K1: LDS-tiled bf16 MFMA GEMM ----------------
// 5 blocks/batch: sub 0->(0,0) 1->(1,0) 2->(1,1) of G -> writes bf16 Gh (all)
// + fp32 Gd for diagonal 16-tiles. sub 3..4 -> P0 row-blocks {0,1} (fp32).
__global__ __launch_bounds__(256)
void k1_gemm(const unsigned short* __restrict__ Xb,
             const unsigned short* __restrict__ Wg,
             float* __restrict__ Gd, unsigned short* __restrict__ Gh,
             float* __restrict__ P0)
{
    __shared__ unsigned short As[128 * 64];
    __shared__ unsigned short Bs[128 * 64];

    const int tid  = threadIdx.x;
    const int lane = tid & 63;
    const int wv   = tid >> 6;
    const int l16  = lane & 15;
    const int quad = lane >> 4;

    const int b   = blockIdx.x & 63;   // same-batch blocks -> same XCD
    const int sub = blockIdx.x >> 6;   // 0..4

    const unsigned short* xbB = Xb + (size_t)b * NT * NI;
    const unsigned short *aRows, *bRows;
    int bm = 0, bn = 0;
    if (sub < 3) {
        bm = (sub >= 1) ? 1 : 0;
        bn = (sub == 2) ? 1 : 0;
        aRows = xbB + (size_t)bm * 128 * NI;
        bRows = xbB + (size_t)bn * 128 * NI;
    } else {
        const int pb = sub - 3;
        bm = pb;
        aRows = xbB + (size_t)pb * 128 * NI;
        bRows = Wg + (size_t)b * NOBS * NI;
    }

    const int wm = (wv >> 1) * 64;
    const int wn = (wv & 1) * 64;

    f32x4 acc[4][4] = {};

    for (int kb = 0; kb < NI / 64; ++kb) {
        __syncthreads();
#pragma unroll
        for (int it = 0; it < 4; ++it) {
            const int s = it * 256 + tid;
            const int m = s >> 3, c = s & 7;
            const int slot = m * 64 + ((c ^ (m & 7)) * 8);
            const size_t goff = (size_t)m * NI + kb * 64 + c * 8;
            *(bf16x8*)&As[slot] = *(const bf16x8*)(aRows + goff);
            *(bf16x8*)&Bs[slot] = *(const bf16x8*)(bRows + goff);
        }
        __syncthreads();
#pragma unroll
        for (int ks = 0; ks < 2; ++ks) {
            const int q = ks * 4 + quad;
            bf16x8 af[4], bfr[4];
#pragma unroll
            for (int mt = 0; mt < 4; ++mt) {
                const int m = wm + mt * 16 + l16;
                af[mt] = *(const bf16x8*)&As[m * 64 + ((q ^ (m & 7)) * 8)];
            }
#pragma unroll
            for (int nt = 0; nt < 4; ++nt) {
                const int n = wn + nt * 16 + l16;
                bfr[nt] = *(const bf16x8*)&Bs[n * 64 + ((q ^ (n & 7)) * 8)];
            }
#pragma unroll
            for (int mt = 0; mt < 4; ++mt)
#pragma unroll
                for (int nt = 0; nt < 4; ++nt)
                    acc[mt][nt] = __builtin_amdgcn_mfma_f32_16x16x32_bf16(
                        af[mt], bfr[nt], acc[mt][nt], 0, 0, 0);
        }
    }

    if (sub < 3) {
        unsigned short* GhB = Gh + ((size_t)b << 16);
        float* GdB = Gd + ((size_t)b << 12);
#pragma unroll
        for (int mt = 0; mt < 4; ++mt)
#pragma unroll
            for (int nt = 0; nt < 4; ++nt) {
                const int gcol = bn * 128 + wn + nt * 16 + l16;
#pragma unroll
                for (int r = 0; r < 4; ++r) {
                    const int grow = bm * 128 + wm + mt * 16 + quad * 4 + r;
                    const float v = acc[mt][nt][r];
                    GhB[(size_t)grow * 256 + gcol] = f2bf(v);
                    if ((grow >> 4) == (gcol >> 4))
                        GdB[((grow >> 4) << 8) + ((grow & 15) << 4) + (gcol & 15)] = v;
                }
            }
    } else {
        float* Pb = P0 + (size_t)b * NT * NOBS + (size_t)bm * 128 * NOBS;
#pragma unroll
        for (int mt = 0; mt < 4; ++mt)
#pragma unroll
            for (int nt = 0; nt < 4; ++nt)
#pragma unroll
                for (int r = 0; r < 4; ++r)
                    Pb[(size_t)(wm + mt * 16 + quad * 4 + r) * NOBS
                       + wn + nt * 16 + l16] = acc[mt][nt][r];
    }
}

// ---------------- K2: latency-optimized MFMA blocked scan ----------------
// block = (b, 16 j's) -> 512 blocks (2/CU), 512 threads (8 waves).
// Wave w holds pre tiles T=2w,2w+1 as MFMA C-fragments.
// ONE barrier per chunk. The chunk loop is deliberately NOT unrolled
// (#pragma unroll 1): fully unrolling inlined ~16 copies of the ~450-inst
// scan body -> 30+ KB of code -> L1I thrash was the round-1 bottleneck
// (all pipes <10% busy). acc[] indexing at call sites kept compile-time
// static via if/else so the fragments stay in VGPRs.
__global__ __launch_bounds__(512, 4)
void k2_scan(const float* __restrict__ Gd, const unsigned short* __restrict__ Gh,
             const float* __restrict__ P0, float* __restrict__ out)
{
    __shared__ float gdiag[16 * 16 * 16];      // 16 KB [c][u][v] fp32
    __shared__ float preS[16 * 17];            // padded transpose buffer
    __shared__ unsigned int ybf2[2 * 8 * 16];  // ping-pong packed eta*y pairs

    const int tid  = threadIdx.x;
    const int lane = tid & 63;
    const int l16  = lane & 15;
    const int quad = lane >> 4;
    const int w    = __builtin_amdgcn_readfirstlane(tid >> 6);

    const int b  = blockIdx.x & 63;            // same-batch blocks -> same XCD
    const int jg = blockIdx.x >> 6;            // 0..7 col-groups of 16

    const float* Pb = P0 + (size_t)b * NT * NOBS + jg * 16;
    const unsigned short* GhB = Gh + ((size_t)b << 16);
    float* ob = out + (size_t)b * NT * NOBS + jg * 16;

    // stage fp32 diag tiles (Gd[b] is 16 KB contiguous).
    // chunk-0 tile (floats 0..255) is written by wave 0 itself (tids 0..63),
    // so the pre-loop scan only needs a wave-local lgkmcnt wait.
    {
        const f32x4* gs = (const f32x4*)(Gd + ((size_t)b << 12));
        ((f32x4*)gdiag)[tid]       = gs[tid];
        ((f32x4*)gdiag)[512 + tid] = gs[512 + tid];
    }

    // init pre C-fragments from P0: D[m=quad*4+r][n=l16]
    f32x4 acc[2];
#pragma unroll
    for (int s2 = 0; s2 < 2; ++s2)
#pragma unroll
        for (int r = 0; r < 4; ++r)
            acc[s2][r] = Pb[(size_t)(w * 32 + s2 * 16 + quad * 4 + r) * NOBS + l16];

    const int T0 = 2 * w, T1 = 2 * w + 1;

    union AB { bf16x8 v; unsigned int d[4]; };
    AB Acur0, Acur1, Anext0, Anext1;
#pragma unroll
    for (int p2 = 0; p2 < 4; ++p2) {
        Acur0.d[p2] = 0; Acur1.d[p2] = 0; Anext0.d[p2] = 0; Anext1.d[p2] = 0;
    }
    // prefetch A(T, c=0)
    if (quad < 2) {
        if (T0 > 0)
            Acur0.v = *(const bf16x8*)(GhB + (size_t)(T0 * 16 + l16) * 256 + quad * 8);
        Acur1.v = *(const bf16x8*)(GhB + (size_t)(T1 * 16 + l16) * 256 + quad * 8);
    }

    // dump one 16x16 fp32 tile through LDS, then 16 lanes run the serial
    // sigmoid scan for chunk c (intra-wave only: lgkmcnt wait, no barrier)
    auto scan_chunk = [&](const int c, const f32x4 a) {
#pragma unroll
        for (int r = 0; r < 4; ++r)
            preS[(quad * 4 + r) * 17 + l16] = a[r];
        asm volatile("s_waitcnt lgkmcnt(0)" ::: "memory");
        if (lane < 16) {
            const int j = lane;
            const int cp = c & 1;
            float p[16];
#pragma unroll
            for (int u = 0; u < 16; ++u) p[u] = preS[u * 17 + j];
            const float* gdc = gdiag + c * 256;
            float eprev = 0.f;
#pragma unroll
            for (int u = 0; u < 16; ++u) {
                const float y = __builtin_amdgcn_rcpf(1.f + __expf(-p[u]));
                ob[(size_t)(c * 16 + u) * NOBS + j] = y;
                const float e = ETA * y;
#pragma unroll
                for (int v = u + 1; v < 16; ++v)
                    p[v] = fmaf(e, gdc[u * 16 + v], p[v]);
                if (u & 1)
                    ybf2[cp * 128 + (u >> 1) * 16 + j] =
                        (unsigned)f2bf(eprev) | ((unsigned)f2bf(e) << 16);
                else
                    eprev = e;
            }
        }
    };

    // chunk 0: owner = wave 0 (tile 0 is P0-only, no updates needed)
    if (w == 0)
        scan_chunk(0, acc[0]);
    __syncthreads();

#pragma unroll 1
    for (int c = 0; c < 15; ++c) {
        if (T1 > c) {   // wave still has live tiles
            // B fragment from ybf2[c&1]: B[k=u][n=j], upper K-half zero
            AB B;
#pragma unroll
            for (int p2 = 0; p2 < 4; ++p2) B.d[p2] = 0;
            if (quad < 2) {
#pragma unroll
                for (int p2 = 0; p2 < 4; ++p2)
                    B.d[p2] = ybf2[(c & 1) * 128 + (quad * 4 + p2) * 16 + l16];
            }
            // prefetch A(T, c+1) for next iteration (covered by MFMA+scan)
#pragma unroll
            for (int p2 = 0; p2 < 4; ++p2) { Anext0.d[p2] = 0; Anext1.d[p2] = 0; }
            if (quad < 2) {
                if (T0 > c + 1)
                    Anext0.v = *(const bf16x8*)(GhB + (size_t)(T0 * 16 + l16) * 256
                                                + (c + 1) * 16 + quad * 8);
                if (T1 > c + 1)
                    Anext1.v = *(const bf16x8*)(GhB + (size_t)(T1 * 16 + l16) * 256
                                                + (c + 1) * 16 + quad * 8);
            }
            // rank-16 updates of this wave's future tiles
            if (T0 > c)
                acc[0] = __builtin_amdgcn_mfma_f32_16x16x32_bf16(
                    Acur0.v, B.v, acc[0], 0, 0, 0);
            acc[1] = __builtin_amdgcn_mfma_f32_16x16x32_bf16(
                Acur1.v, B.v, acc[1], 0, 0, 0);
            // owner of chunk c+1 scans it now (its own tile is fully updated),
            // overlapping the other waves' update work until the barrier.
            // if/else keeps the acc[] index compile-time static (no scratch).
            if (w == ((c + 1) >> 1)) {
                if ((c + 1) & 1) scan_chunk(c + 1, acc[1]);
                else             scan_chunk(c + 1, acc[0]);
            }
            Acur0 = Anext0;
            Acur1 = Anext1;
        }
        __syncthreads();
    }
}

extern "C" void kernel_launch(void* const* d_in, const int* in_sizes, int n_in,
                              void* d_out, int out_size, void* d_ws, size_t ws_size,
                              hipStream_t stream)
{
    const float* X   = (const float*)d_in[0];
    const float* Wi  = (const float*)d_in[1];
    const int*   obs = (const int*)d_in[2];
    float*       out = (float*)d_out;

    float*          Gd = (float*)d_ws;                                  //  1 MB
    float*          P0 = (float*)((char*)d_ws + (1u << 20));            //  8 MB
    unsigned short* Gh = (unsigned short*)((char*)d_ws + (9u << 20));   //  8 MB
    unsigned short* Xb = (unsigned short*)((char*)d_ws + (17u << 20));  // 16 MB
    unsigned short* Wg = (unsigned short*)((char*)d_ws + (33u << 20));  //  8 MB

    hipLaunchKernelGGL(k0_convert, dim3(3072), dim3(256), 0, stream,
                       X, Wi, obs, Xb, Wg);
    hipLaunchKernelGGL(k1_gemm, dim3(NB * 5), dim3(256), 0, stream,
                       Xb, Wg, Gd, Gh, P0);
    hipLaunchKernelGGL(k2_scan, dim3(NB * 8), dim3(512), 0, stream,
                       Gd, Gh, P0, out);
}

// Round 3
// 155.314 us; speedup vs baseline: 1.0272x; 1.0272x over previous
//
#include <hip/hip_runtime.h>

#define NB   64
#define NT   256
#define NI   512
#define NO   512
#define NOBS 128
#define ETA  0.01f

typedef __attribute__((ext_vector_type(8))) short bf16x8;
typedef __attribute__((ext_vector_type(4))) float f32x4;

#define X4_COUNT  (NB*NT*NI/4)
#define WG4_COUNT (NB*NOBS*NI/4)
#define K0_TOTAL  (X4_COUNT + WG4_COUNT)

__device__ __forceinline__ unsigned short f2bf(float f) {
    unsigned int u = __float_as_uint(f);
    return (unsigned short)((u + 0x7fffu + ((u >> 16) & 1u)) >> 16); // RNE
}

// ---------------- K0: X -> bf16 ; gather obs rows of W -> bf16 ----------------
__global__ __launch_bounds__(256)
void k0_convert(const float* __restrict__ X, const float* __restrict__ Wi,
                const int* __restrict__ obs,
                unsigned short* __restrict__ Xb, unsigned short* __restrict__ Wg)
{
    int idx = blockIdx.x * 256 + threadIdx.x;
    const int stride = gridDim.x * 256;
    for (; idx < K0_TOTAL; idx += stride) {
        float4 v; ushort4* dst;
        if (idx < X4_COUNT) {
            v = ((const float4*)X)[idx];
            dst = (ushort4*)Xb + idx;
        } else {
            int g = idx - X4_COUNT;
            int row = g >> 7, pos = g & 127;
            int b = row >> 7, j = row & 127;
            v = ((const float4*)(Wi + ((size_t)b * NO + obs[j]) * NI))[pos];
            dst = (ushort4*)Wg + ((size_t)row * 128 + pos);
        }
        *dst = make_ushort4(f2bf(v.x), f2bf(v.y), f2bf(v.z), f2bf(v.w));
    }
}

// ---------------- K1: LDS-tiled bf16 MFMA GEMM ----------------
// 5 blocks/batch: sub 0->(0,0) 1->(1,0) 2->(1,1) of G -> writes bf16 Gh (all)
// + fp32 Gd for diagonal 16-tiles. sub 3..4 -> P0 row-blocks {0,1} (fp32).
// NOTE: ETA is folded into Gh/Gd here (k2's scan then uses e = y directly,
// removing one dependent VALU op per serial-scan step; MFMA product A*B is
// unchanged since B now packs y instead of ETA*y).
__global__ __launch_bounds__(256)
void k1_gemm(const unsigned short* __restrict__ Xb,
             const unsigned short* __restrict__ Wg,
             float* __restrict__ Gd, unsigned short* __restrict__ Gh,
             float* __restrict__ P0)
{
    __shared__ unsigned short As[128 * 64];
    __shared__ unsigned short Bs[128 * 64];

    const int tid  = threadIdx.x;
    const int lane = tid & 63;
    const int wv   = tid >> 6;
    const int l16  = lane & 15;
    const int quad = lane >> 4;

    const int b   = blockIdx.x & 63;   // same-batch blocks -> same XCD
    const int sub = blockIdx.x >> 6;   // 0..4

    const unsigned short* xbB = Xb + (size_t)b * NT * NI;
    const unsigned short *aRows, *bRows;
    int bm = 0, bn = 0;
    if (sub < 3) {
        bm = (sub >= 1) ? 1 : 0;
        bn = (sub == 2) ? 1 : 0;
        aRows = xbB + (size_t)bm * 128 * NI;
        bRows = xbB + (size_t)bn * 128 * NI;
    } else {
        const int pb = sub - 3;
        bm = pb;
        aRows = xbB + (size_t)pb * 128 * NI;
        bRows = Wg + (size_t)b * NOBS * NI;
    }

    const int wm = (wv >> 1) * 64;
    const int wn = (wv & 1) * 64;

    f32x4 acc[4][4] = {};

    for (int kb = 0; kb < NI / 64; ++kb) {
        __syncthreads();
#pragma unroll
        for (int it = 0; it < 4; ++it) {
            const int s = it * 256 + tid;
            const int m = s >> 3, c = s & 7;
            const int slot = m * 64 + ((c ^ (m & 7)) * 8);
            const size_t goff = (size_t)m * NI + kb * 64 + c * 8;
            *(bf16x8*)&As[slot] = *(const bf16x8*)(aRows + goff);
            *(bf16x8*)&Bs[slot] = *(const bf16x8*)(bRows + goff);
        }
        __syncthreads();
#pragma unroll
        for (int ks = 0; ks < 2; ++ks) {
            const int q = ks * 4 + quad;
            bf16x8 af[4], bfr[4];
#pragma unroll
            for (int mt = 0; mt < 4; ++mt) {
                const int m = wm + mt * 16 + l16;
                af[mt] = *(const bf16x8*)&As[m * 64 + ((q ^ (m & 7)) * 8)];
            }
#pragma unroll
            for (int nt = 0; nt < 4; ++nt) {
                const int n = wn + nt * 16 + l16;
                bfr[nt] = *(const bf16x8*)&Bs[n * 64 + ((q ^ (n & 7)) * 8)];
            }
#pragma unroll
            for (int mt = 0; mt < 4; ++mt)
#pragma unroll
                for (int nt = 0; nt < 4; ++nt)
                    acc[mt][nt] = __builtin_amdgcn_mfma_f32_16x16x32_bf16(
                        af[mt], bfr[nt], acc[mt][nt], 0, 0, 0);
        }
    }

    if (sub < 3) {
        unsigned short* GhB = Gh + ((size_t)b << 16);
        float* GdB = Gd + ((size_t)b << 12);
#pragma unroll
        for (int mt = 0; mt < 4; ++mt)
#pragma unroll
            for (int nt = 0; nt < 4; ++nt) {
                const int gcol = bn * 128 + wn + nt * 16 + l16;
#pragma unroll
                for (int r = 0; r < 4; ++r) {
                    const int grow = bm * 128 + wm + mt * 16 + quad * 4 + r;
                    const float v = ETA * acc[mt][nt][r];   // ETA folded here
                    GhB[(size_t)grow * 256 + gcol] = f2bf(v);
                    if ((grow >> 4) == (gcol >> 4))
                        GdB[((grow >> 4) << 8) + ((grow & 15) << 4) + (gcol & 15)] = v;
                }
            }
    } else {
        float* Pb = P0 + (size_t)b * NT * NOBS + (size_t)bm * 128 * NOBS;
#pragma unroll
        for (int mt = 0; mt < 4; ++mt)
#pragma unroll
            for (int nt = 0; nt < 4; ++nt)
#pragma unroll
                for (int r = 0; r < 4; ++r)
                    Pb[(size_t)(wm + mt * 16 + quad * 4 + r) * NOBS
                       + wn + nt * 16 + l16] = acc[mt][nt][r];
    }
}

// ---------------- K2: latency-optimized MFMA blocked scan ----------------
// block = (b, 16 j's) -> 512 blocks (2/CU), 512 threads (8 waves).
// Round-2 post-mortem: k2 pinned at 40-42us across 3 structural variants;
// VALUBusy 15% => 85% stall. Cause: each of the 256 serial timesteps exposed
// a ~120cy LDS read of the G row on the dependent chain (compiler never
// hoisted them; VGPR_Count was 36). Fix: explicit 2-step-ahead software
// pipeline of G rows into 3 rotating register buffers (all static indices),
// ETA pre-folded into G (k1), s_setprio(1) around the scan.

// Load row U1 of the chunk's 16x16 G tile into 4 f32x4 (only quarters that
// contain some v >= U1+1; conditions are compile-time constants).
#define LDROW(Q0, Q1, Q2, Q3, U1)                                          \
    {                                                                      \
        if ((U1) <= 14) {                                                  \
            if ((U1) <= 2)  Q0 = *(const f32x4*)(gdc + (U1) * 16);         \
            if ((U1) <= 6)  Q1 = *(const f32x4*)(gdc + (U1) * 16 + 4);     \
            if ((U1) <= 10) Q2 = *(const f32x4*)(gdc + (U1) * 16 + 8);     \
            Q3 = *(const f32x4*)(gdc + (U1) * 16 + 12);                    \
        }                                                                  \
    }

// Element v of a row held in 4 quarters (V is compile-time after unroll).
#define GV(Q0, Q1, Q2, Q3, V)                                              \
    ((V) < 4 ? (Q0)[(V) & 3] : (V) < 8 ? (Q1)[(V) & 3]                     \
             : (V) < 12 ? (Q2)[(V) & 3] : (Q3)[(V) & 3])

// One serial timestep: prefetch row U+2 (off-chain), sigmoid (chain),
// rank-1 update of remaining p's, pack bf16 y pairs for the MFMA phase.
#define SCAN_STEP(U, C0, C1, C2, C3, N0, N1, N2, N3)                       \
    {                                                                      \
        LDROW(N0, N1, N2, N3, (U) + 2)                                     \
        const float y = __builtin_amdgcn_rcpf(1.f + __expf(-p[(U)]));      \
        ob[obOff + (size_t)((U) * NOBS)] = y;                              \
        _Pragma("unroll")                                                  \
        for (int v = (U) + 1; v < 16; ++v)                                 \
            p[v] = fmaf(y, GV(C0, C1, C2, C3, v), p[v]);                   \
        if ((U) & 1)                                                       \
            ybf2[cp * 128 + ((U) >> 1) * 16 + j] =                         \
                (unsigned)f2bf(eprev) | ((unsigned)f2bf(y) << 16);         \
        else                                                               \
            eprev = y;                                                     \
    }

__global__ __launch_bounds__(512, 4)
void k2_scan(const float* __restrict__ Gd, const unsigned short* __restrict__ Gh,
             const float* __restrict__ P0, float* __restrict__ out)
{
    __shared__ float gdiag[16 * 16 * 16];      // 16 KB [c][u][v] fp32 (= ETA*G)
    __shared__ float preS[16 * 17];            // padded transpose buffer
    __shared__ unsigned int ybf2[2 * 8 * 16];  // ping-pong packed y pairs

    const int tid  = threadIdx.x;
    const int lane = tid & 63;
    const int l16  = lane & 15;
    const int quad = lane >> 4;
    const int w    = __builtin_amdgcn_readfirstlane(tid >> 6);

    const int b  = blockIdx.x & 63;            // same-batch blocks -> same XCD
    const int jg = blockIdx.x >> 6;            // 0..7 col-groups of 16

    const float* Pb = P0 + (size_t)b * NT * NOBS + jg * 16;
    const unsigned short* GhB = Gh + ((size_t)b << 16);
    float* ob = out + (size_t)b * NT * NOBS + jg * 16;

    // stage fp32 diag tiles (Gd[b] is 16 KB contiguous).
    // chunk-0 tile (floats 0..255) is written by wave 0 itself (tids 0..63),
    // so the pre-loop scan only needs a wave-local lgkmcnt wait.
    {
        const f32x4* gs = (const f32x4*)(Gd + ((size_t)b << 12));
        ((f32x4*)gdiag)[tid]       = gs[tid];
        ((f32x4*)gdiag)[512 + tid] = gs[512 + tid];
    }

    // init pre C-fragments from P0: D[m=quad*4+r][n=l16]
    f32x4 acc[2];
#pragma unroll
    for (int s2 = 0; s2 < 2; ++s2)
#pragma unroll
        for (int r = 0; r < 4; ++r)
            acc[s2][r] = Pb[(size_t)(w * 32 + s2 * 16 + quad * 4 + r) * NOBS + l16];

    const int T0 = 2 * w, T1 = 2 * w + 1;

    union AB { bf16x8 v; unsigned int d[4]; };
    AB Acur0, Acur1, Anext0, Anext1;
#pragma unroll
    for (int p2 = 0; p2 < 4; ++p2) {
        Acur0.d[p2] = 0; Acur1.d[p2] = 0; Anext0.d[p2] = 0; Anext1.d[p2] = 0;
    }
    // prefetch A(T, c=0)
    if (quad < 2) {
        if (T0 > 0)
            Acur0.v = *(const bf16x8*)(GhB + (size_t)(T0 * 16 + l16) * 256 + quad * 8);
        Acur1.v = *(const bf16x8*)(GhB + (size_t)(T1 * 16 + l16) * 256 + quad * 8);
    }

    // dump one 16x16 fp32 tile through LDS, then 16 lanes run the serial
    // sigmoid scan for chunk c (intra-wave only: lgkmcnt wait, no barrier)
    auto scan_chunk = [&](const int c, const f32x4 a) {
#pragma unroll
        for (int r = 0; r < 4; ++r)
            preS[(quad * 4 + r) * 17 + l16] = a[r];
        asm volatile("s_waitcnt lgkmcnt(0)" ::: "memory");
        __builtin_amdgcn_s_setprio(1);
        if (lane < 16) {
            const int j = lane;
            const int cp = c & 1;
            const float* gdc = gdiag + (c << 8);
            const size_t obOff = (size_t)(c << 4) * NOBS + j;
            float p[16];
#pragma unroll
            for (int u = 0; u < 16; ++u) p[u] = preS[u * 17 + j];
            // 3 rotating row buffers, loads issued 2 steps ahead of use
            f32x4 Aq0, Aq1, Aq2, Aq3, Bq0, Bq1, Bq2, Bq3, Cq0, Cq1, Cq2, Cq3;
            LDROW(Aq0, Aq1, Aq2, Aq3, 0)
            LDROW(Bq0, Bq1, Bq2, Bq3, 1)
            float eprev = 0.f;
            SCAN_STEP(0,  Aq0, Aq1, Aq2, Aq3, Cq0, Cq1, Cq2, Cq3)
            SCAN_STEP(1,  Bq0, Bq1, Bq2, Bq3, Aq0, Aq1, Aq2, Aq3)
            SCAN_STEP(2,  Cq0, Cq1, Cq2, Cq3, Bq0, Bq1, Bq2, Bq3)
            SCAN_STEP(3,  Aq0, Aq1, Aq2, Aq3, Cq0, Cq1, Cq2, Cq3)
            SCAN_STEP(4,  Bq0, Bq1, Bq2, Bq3, Aq0, Aq1, Aq2, Aq3)
            SCAN_STEP(5,  Cq0, Cq1, Cq2, Cq3, Bq0, Bq1, Bq2, Bq3)
            SCAN_STEP(6,  Aq0, Aq1, Aq2, Aq3, Cq0, Cq1, Cq2, Cq3)
            SCAN_STEP(7,  Bq0, Bq1, Bq2, Bq3, Aq0, Aq1, Aq2, Aq3)
            SCAN_STEP(8,  Cq0, Cq1, Cq2, Cq3, Bq0, Bq1, Bq2, Bq3)
            SCAN_STEP(9,  Aq0, Aq1, Aq2, Aq3, Cq0, Cq1, Cq2, Cq3)
            SCAN_STEP(10, Bq0, Bq1, Bq2, Bq3, Aq0, Aq1, Aq2, Aq3)
            SCAN_STEP(11, Cq0, Cq1, Cq2, Cq3, Bq0, Bq1, Bq2, Bq3)
            SCAN_STEP(12, Aq0, Aq1, Aq2, Aq3, Cq0, Cq1, Cq2, Cq3)
            SCAN_STEP(13, Bq0, Bq1, Bq2, Bq3, Aq0, Aq1, Aq2, Aq3)
            SCAN_STEP(14, Cq0, Cq1, Cq2, Cq3, Bq0, Bq1, Bq2, Bq3)
            SCAN_STEP(15, Aq0, Aq1, Aq2, Aq3, Cq0, Cq1, Cq2, Cq3)
        }
        __builtin_amdgcn_s_setprio(0);
    };

    // chunk 0: owner = wave 0 (tile 0 is P0-only, no updates needed)
    if (w == 0)
        scan_chunk(0, acc[0]);
    __syncthreads();

#pragma unroll 1
    for (int c = 0; c < 15; ++c) {
        if (T1 > c) {   // wave still has live tiles
            // B fragment from ybf2[c&1]: B[k=u][n=j], upper K-half zero
            AB B;
#pragma unroll
            for (int p2 = 0; p2 < 4; ++p2) B.d[p2] = 0;
            if (quad < 2) {
#pragma unroll
                for (int p2 = 0; p2 < 4; ++p2)
                    B.d[p2] = ybf2[(c & 1) * 128 + (quad * 4 + p2) * 16 + l16];
            }
            // prefetch A(T, c+1) for next iteration (covered by MFMA+scan)
#pragma unroll
            for (int p2 = 0; p2 < 4; ++p2) { Anext0.d[p2] = 0; Anext1.d[p2] = 0; }
            if (quad < 2) {
                if (T0 > c + 1)
                    Anext0.v = *(const bf16x8*)(GhB + (size_t)(T0 * 16 + l16) * 256
                                                + (c + 1) * 16 + quad * 8);
                if (T1 > c + 1)
                    Anext1.v = *(const bf16x8*)(GhB + (size_t)(T1 * 16 + l16) * 256
                                                + (c + 1) * 16 + quad * 8);
            }
            // rank-16 updates of this wave's future tiles
            if (T0 > c)
                acc[0] = __builtin_amdgcn_mfma_f32_16x16x32_bf16(
                    Acur0.v, B.v, acc[0], 0, 0, 0);
            acc[1] = __builtin_amdgcn_mfma_f32_16x16x32_bf16(
                Acur1.v, B.v, acc[1], 0, 0, 0);
            // owner of chunk c+1 scans it now (its own tile is fully updated),
            // overlapping the other waves' update work until the barrier.
            // if/else keeps the acc[] index compile-time static (no scratch).
            if (w == ((c + 1) >> 1)) {
                if ((c + 1) & 1) scan_chunk(c + 1, acc[1]);
                else             scan_chunk(c + 1, acc[0]);
            }
            Acur0 = Anext0;
            Acur1 = Anext1;
        }
        __syncthreads();
    }
}

extern "C" void kernel_launch(void* const* d_in, const int* in_sizes, int n_in,
                              void* d_out, int out_size, void* d_ws, size_t ws_size,
                              hipStream_t stream)
{
    const float* X   = (const float*)d_in[0];
    const float* Wi  = (const float*)d_in[1];
    const int*   obs = (const int*)d_in[2];
    float*       out = (float*)d_out;

    float*          Gd = (float*)d_ws;                                  //  1 MB
    float*          P0 = (float*)((char*)d_ws + (1u << 20));            //  8 MB
    unsigned short* Gh = (unsigned short*)((char*)d_ws + (9u << 20));   //  8 MB
    unsigned short* Xb = (unsigned short*)((char*)d_ws + (17u << 20));  // 16 MB
    unsigned short* Wg = (unsigned short*)((char*)d_ws + (33u << 20));  //  8 MB

    hipLaunchKernelGGL(k0_convert, dim3(3072), dim3(256), 0, stream,
                       X, Wi, obs, Xb, Wg);
    hipLaunchKernelGGL(k1_gemm, dim3(NB * 5), dim3(256), 0, stream,
                       Xb, Wg, Gd, Gh, P0);
    hipLaunchKernelGGL(k2_scan, dim3(NB * 8), dim3(512), 0, stream,
                       Gd, Gh, P0, out);
}

// Round 4
// 146.649 us; speedup vs baseline: 1.0879x; 1.0591x over previous
//
#include <hip/hip_runtime.h>

#define NB   64
#define NT   256
#define NI   512
#define NO   512
#define NOBS 128
#define ETA  0.01f

typedef __attribute__((ext_vector_type(8))) short bf16x8;
typedef __attribute__((ext_vector_type(4))) float f32x4;

__device__ __forceinline__ unsigned short f2bf(float f) {
    unsigned int u = __float_as_uint(f);
    return (unsigned short)((u + 0x7fffu + ((u >> 16) & 1u)) >> 16); // RNE
}

// packed fp32x2 -> bf16x2 (RNE, same bits as f2bf); no builtin on gfx950
__device__ __forceinline__ unsigned cvtpk(float lo, float hi) {
    unsigned r;
    asm("v_cvt_pk_bf16_f32 %0, %1, %2" : "=v"(r) : "v"(lo), "v"(hi));
    return r;
}

// ---------------- K1: fused convert + LDS-tiled bf16 MFMA GEMM ----------------
// k0 is GONE: staging reads fp32 X / gathered fp32 Wi rows directly and
// converts to bf16 with v_cvt_pk_bf16_f32 while writing LDS. Saves the
// 32 MB Xb write + re-read and 8 MB Wg round-trip plus a kernel launch.
// 5 blocks/batch: sub 0->(0,0) 1->(1,0) 2->(1,1) of G -> writes bf16 Gh (all)
// + fp32 Gd for diagonal 16-tiles. sub 3..4 -> P0 row-blocks {0,1} (fp32).
// ETA is folded into Gh/Gd here (k2's scan uses e = y directly; the MFMA
// product A*B is unchanged since B packs y instead of ETA*y).
__global__ __launch_bounds__(256)
void k1_gemm(const float* __restrict__ Xf, const float* __restrict__ Wf,
             const int* __restrict__ obs,
             float* __restrict__ Gd, unsigned short* __restrict__ Gh,
             float* __restrict__ P0)
{
    __shared__ unsigned short As[128 * 64];
    __shared__ unsigned short Bs[128 * 64];
    __shared__ int obsS[128];

    const int tid  = threadIdx.x;
    const int lane = tid & 63;
    const int wv   = tid >> 6;
    const int l16  = lane & 15;
    const int quad = lane >> 4;

    const int b   = blockIdx.x & 63;   // same-batch blocks -> same XCD
    const int sub = blockIdx.x >> 6;   // 0..4

    if (tid < 128) obsS[tid] = obs[tid];
    __syncthreads();

    int bm = 0, bn = 0;
    if (sub < 3) {
        bm = (sub >= 1) ? 1 : 0;
        bn = (sub == 2) ? 1 : 0;
    } else {
        bm = sub - 3;
    }

    // per-thread staging geometry (kb-invariant): thread covers 8 floats of
    // row m = it*32 + (tid>>3), cols (tid&7)*8.. ; swizzled LDS slot.
    const int mrow = tid >> 3;
    const int ccol = tid & 7;
    const float* aP[4];
    const float* bP[4];
    int slotv[4];
#pragma unroll
    for (int it = 0; it < 4; ++it) {
        const int m = it * 32 + mrow;
        slotv[it] = m * 64 + ((ccol ^ (m & 7)) * 8);
        aP[it] = Xf + ((size_t)b * NT + bm * 128 + m) * NI + ccol * 8;
        bP[it] = (sub < 3)
                   ? Xf + ((size_t)b * NT + bn * 128 + m) * NI + ccol * 8
                   : Wf + ((size_t)b * NO + obsS[m]) * NI + ccol * 8;
    }

    const int wm = (wv >> 1) * 64;
    const int wn = (wv & 1) * 64;

    f32x4 acc[4][4] = {};

    for (int kb = 0; kb < NI / 64; ++kb) {
        __syncthreads();
#pragma unroll
        for (int it = 0; it < 4; ++it) {
            const float4 a0 = *(const float4*)(aP[it]);
            const float4 a1 = *(const float4*)(aP[it] + 4);
            const float4 b0 = *(const float4*)(bP[it]);
            const float4 b1 = *(const float4*)(bP[it] + 4);
            uint4 ap, bp;
            ap.x = cvtpk(a0.x, a0.y); ap.y = cvtpk(a0.z, a0.w);
            ap.z = cvtpk(a1.x, a1.y); ap.w = cvtpk(a1.z, a1.w);
            bp.x = cvtpk(b0.x, b0.y); bp.y = cvtpk(b0.z, b0.w);
            bp.z = cvtpk(b1.x, b1.y); bp.w = cvtpk(b1.z, b1.w);
            *(uint4*)&As[slotv[it]] = ap;
            *(uint4*)&Bs[slotv[it]] = bp;
            aP[it] += 64;
            bP[it] += 64;
        }
        __syncthreads();
#pragma unroll
        for (int ks = 0; ks < 2; ++ks) {
            const int q = ks * 4 + quad;
            bf16x8 af[4], bfr[4];
#pragma unroll
            for (int mt = 0; mt < 4; ++mt) {
                const int m = wm + mt * 16 + l16;
                af[mt] = *(const bf16x8*)&As[m * 64 + ((q ^ (m & 7)) * 8)];
            }
#pragma unroll
            for (int nt = 0; nt < 4; ++nt) {
                const int n = wn + nt * 16 + l16;
                bfr[nt] = *(const bf16x8*)&Bs[n * 64 + ((q ^ (n & 7)) * 8)];
            }
#pragma unroll
            for (int mt = 0; mt < 4; ++mt)
#pragma unroll
                for (int nt = 0; nt < 4; ++nt)
                    acc[mt][nt] = __builtin_amdgcn_mfma_f32_16x16x32_bf16(
                        af[mt], bfr[nt], acc[mt][nt], 0, 0, 0);
        }
    }

    if (sub < 3) {
        unsigned short* GhB = Gh + ((size_t)b << 16);
        float* GdB = Gd + ((size_t)b << 12);
#pragma unroll
        for (int mt = 0; mt < 4; ++mt)
#pragma unroll
            for (int nt = 0; nt < 4; ++nt) {
                const int gcol = bn * 128 + wn + nt * 16 + l16;
#pragma unroll
                for (int r = 0; r < 4; ++r) {
                    const int grow = bm * 128 + wm + mt * 16 + quad * 4 + r;
                    const float v = ETA * acc[mt][nt][r];   // ETA folded here
                    GhB[(size_t)grow * 256 + gcol] = f2bf(v);
                    if ((grow >> 4) == (gcol >> 4))
                        GdB[((grow >> 4) << 8) + ((grow & 15) << 4) + (gcol & 15)] = v;
                }
            }
    } else {
        float* Pb = P0 + (size_t)b * NT * NOBS + (size_t)bm * 128 * NOBS;
#pragma unroll
        for (int mt = 0; mt < 4; ++mt)
#pragma unroll
            for (int nt = 0; nt < 4; ++nt)
#pragma unroll
                for (int r = 0; r < 4; ++r)
                    Pb[(size_t)(wm + mt * 16 + quad * 4 + r) * NOBS
                       + wn + nt * 16 + l16] = acc[mt][nt][r];
    }
}

// ---------------- K2: latency-optimized MFMA blocked scan ----------------
// block = (b, 16 j's) -> 512 blocks (2/CU), 512 threads (8 waves).
// Serial scan runs with G rows software-pipelined 2 steps ahead into 3
// rotating register row-buffers (round-3 win: removed ~120cy LDS latency
// from the 256-step dependent chain). ETA pre-folded into G (k1).

#define LDROW(Q0, Q1, Q2, Q3, U1)                                          \
    {                                                                      \
        if ((U1) <= 14) {                                                  \
            if ((U1) <= 2)  Q0 = *(const f32x4*)(gdc + (U1) * 16);         \
            if ((U1) <= 6)  Q1 = *(const f32x4*)(gdc + (U1) * 16 + 4);     \
            if ((U1) <= 10) Q2 = *(const f32x4*)(gdc + (U1) * 16 + 8);     \
            Q3 = *(const f32x4*)(gdc + (U1) * 16 + 12);                    \
        }                                                                  \
    }

#define GV(Q0, Q1, Q2, Q3, V)                                              \
    ((V) < 4 ? (Q0)[(V) & 3] : (V) < 8 ? (Q1)[(V) & 3]                     \
             : (V) < 12 ? (Q2)[(V) & 3] : (Q3)[(V) & 3])

#define SCAN_STEP(U, C0, C1, C2, C3, N0, N1, N2, N3)                       \
    {                                                                      \
        LDROW(N0, N1, N2, N3, (U) + 2)                                     \
        const float y = __builtin_amdgcn_rcpf(1.f + __expf(-p[(U)]));      \
        ob[obOff + (size_t)((U) * NOBS)] = y;                              \
        _Pragma("unroll")                                                  \
        for (int v = (U) + 1; v < 16; ++v)                                 \
            p[v] = fmaf(y, GV(C0, C1, C2, C3, v), p[v]);                   \
        if ((U) & 1)                                                       \
            ybf2[cp * 128 + ((U) >> 1) * 16 + j] =                         \
                (unsigned)f2bf(eprev) | ((unsigned)f2bf(y) << 16);         \
        else                                                               \
            eprev = y;                                                     \
    }

__global__ __launch_bounds__(512, 4)
void k2_scan(const float* __restrict__ Gd, const unsigned short* __restrict__ Gh,
             const float* __restrict__ P0, float* __restrict__ out)
{
    __shared__ float gdiag[16 * 16 * 16];      // 16 KB [c][u][v] fp32 (= ETA*G)
    __shared__ float preS[16 * 17];            // padded transpose buffer
    __shared__ unsigned int ybf2[2 * 8 * 16];  // ping-pong packed y pairs

    const int tid  = threadIdx.x;
    const int lane = tid & 63;
    const int l16  = lane & 15;
    const int quad = lane >> 4;
    const int w    = __builtin_amdgcn_readfirstlane(tid >> 6);

    const int b  = blockIdx.x & 63;            // same-batch blocks -> same XCD
    const int jg = blockIdx.x >> 6;            // 0..7 col-groups of 16

    const float* Pb = P0 + (size_t)b * NT * NOBS + jg * 16;
    const unsigned short* GhB = Gh + ((size_t)b << 16);
    float* ob = out + (size_t)b * NT * NOBS + jg * 16;

    // stage fp32 diag tiles (Gd[b] is 16 KB contiguous).
    // chunk-0 tile (floats 0..255) is written by wave 0 itself (tids 0..63),
    // so the pre-loop scan only needs a wave-local lgkmcnt wait.
    {
        const f32x4* gs = (const f32x4*)(Gd + ((size_t)b << 12));
        ((f32x4*)gdiag)[tid]       = gs[tid];
        ((f32x4*)gdiag)[512 + tid] = gs[512 + tid];
    }

    // init pre C-fragments from P0: D[m=quad*4+r][n=l16]
    f32x4 acc[2];
#pragma unroll
    for (int s2 = 0; s2 < 2; ++s2)
#pragma unroll
        for (int r = 0; r < 4; ++r)
            acc[s2][r] = Pb[(size_t)(w * 32 + s2 * 16 + quad * 4 + r) * NOBS + l16];

    const int T0 = 2 * w, T1 = 2 * w + 1;

    union AB { bf16x8 v; unsigned int d[4]; };
    AB Acur0, Acur1, Anext0, Anext1;
#pragma unroll
    for (int p2 = 0; p2 < 4; ++p2) {
        Acur0.d[p2] = 0; Acur1.d[p2] = 0; Anext0.d[p2] = 0; Anext1.d[p2] = 0;
    }
    // prefetch A(T, c=0)
    if (quad < 2) {
        if (T0 > 0)
            Acur0.v = *(const bf16x8*)(GhB + (size_t)(T0 * 16 + l16) * 256 + quad * 8);
        Acur1.v = *(const bf16x8*)(GhB + (size_t)(T1 * 16 + l16) * 256 + quad * 8);
    }

    // dump one 16x16 fp32 tile through LDS, then 16 lanes run the serial
    // sigmoid scan for chunk c (intra-wave only: lgkmcnt wait, no barrier)
    auto scan_chunk = [&](const int c, const f32x4 a) {
#pragma unroll
        for (int r = 0; r < 4; ++r)
            preS[(quad * 4 + r) * 17 + l16] = a[r];
        asm volatile("s_waitcnt lgkmcnt(0)" ::: "memory");
        __builtin_amdgcn_s_setprio(1);
        if (lane < 16) {
            const int j = lane;
            const int cp = c & 1;
            const float* gdc = gdiag + (c << 8);
            const size_t obOff = (size_t)(c << 4) * NOBS + j;
            float p[16];
#pragma unroll
            for (int u = 0; u < 16; ++u) p[u] = preS[u * 17 + j];
            // 3 rotating row buffers, loads issued 2 steps ahead of use
            f32x4 Aq0, Aq1, Aq2, Aq3, Bq0, Bq1, Bq2, Bq3, Cq0, Cq1, Cq2, Cq3;
            LDROW(Aq0, Aq1, Aq2, Aq3, 0)
            LDROW(Bq0, Bq1, Bq2, Bq3, 1)
            float eprev = 0.f;
            SCAN_STEP(0,  Aq0, Aq1, Aq2, Aq3, Cq0, Cq1, Cq2, Cq3)
            SCAN_STEP(1,  Bq0, Bq1, Bq2, Bq3, Aq0, Aq1, Aq2, Aq3)
            SCAN_STEP(2,  Cq0, Cq1, Cq2, Cq3, Bq0, Bq1, Bq2, Bq3)
            SCAN_STEP(3,  Aq0, Aq1, Aq2, Aq3, Cq0, Cq1, Cq2, Cq3)
            SCAN_STEP(4,  Bq0, Bq1, Bq2, Bq3, Aq0, Aq1, Aq2, Aq3)
            SCAN_STEP(5,  Cq0, Cq1, Cq2, Cq3, Bq0, Bq1, Bq2, Bq3)
            SCAN_STEP(6,  Aq0, Aq1, Aq2, Aq3, Cq0, Cq1, Cq2, Cq3)
            SCAN_STEP(7,  Bq0, Bq1, Bq2, Bq3, Aq0, Aq1, Aq2, Aq3)
            SCAN_STEP(8,  Cq0, Cq1, Cq2, Cq3, Bq0, Bq1, Bq2, Bq3)
            SCAN_STEP(9,  Aq0, Aq1, Aq2, Aq3, Cq0, Cq1, Cq2, Cq3)
            SCAN_STEP(10, Bq0, Bq1, Bq2, Bq3, Aq0, Aq1, Aq2, Aq3)
            SCAN_STEP(11, Cq0, Cq1, Cq2, Cq3, Bq0, Bq1, Bq2, Bq3)
            SCAN_STEP(12, Aq0, Aq1, Aq2, Aq3, Cq0, Cq1, Cq2, Cq3)
            SCAN_STEP(13, Bq0, Bq1, Bq2, Bq3, Aq0, Aq1, Aq2, Aq3)
            SCAN_STEP(14, Cq0, Cq1, Cq2, Cq3, Bq0, Bq1, Bq2, Bq3)
            SCAN_STEP(15, Aq0, Aq1, Aq2, Aq3, Cq0, Cq1, Cq2, Cq3)
        }
        __builtin_amdgcn_s_setprio(0);
    };

    // chunk 0: owner = wave 0 (tile 0 is P0-only, no updates needed)
    if (w == 0)
        scan_chunk(0, acc[0]);
    __syncthreads();

#pragma unroll 1
    for (int c = 0; c < 15; ++c) {
        if (T1 > c) {   // wave still has live tiles
            // B fragment from ybf2[c&1]: B[k=u][n=j], upper K-half zero
            AB B;
#pragma unroll
            for (int p2 = 0; p2 < 4; ++p2) B.d[p2] = 0;
            if (quad < 2) {
#pragma unroll
                for (int p2 = 0; p2 < 4; ++p2)
                    B.d[p2] = ybf2[(c & 1) * 128 + (quad * 4 + p2) * 16 + l16];
            }
            // prefetch A(T, c+1) for next iteration (covered by MFMA+scan)
#pragma unroll
            for (int p2 = 0; p2 < 4; ++p2) { Anext0.d[p2] = 0; Anext1.d[p2] = 0; }
            if (quad < 2) {
                if (T0 > c + 1)
                    Anext0.v = *(const bf16x8*)(GhB + (size_t)(T0 * 16 + l16) * 256
                                                + (c + 1) * 16 + quad * 8);
                if (T1 > c + 1)
                    Anext1.v = *(const bf16x8*)(GhB + (size_t)(T1 * 16 + l16) * 256
                                                + (c + 1) * 16 + quad * 8);
            }
            // rank-16 updates of this wave's future tiles
            if (T0 > c)
                acc[0] = __builtin_amdgcn_mfma_f32_16x16x32_bf16(
                    Acur0.v, B.v, acc[0], 0, 0, 0);
            acc[1] = __builtin_amdgcn_mfma_f32_16x16x32_bf16(
                Acur1.v, B.v, acc[1], 0, 0, 0);
            // owner of chunk c+1 scans it now (its own tile is fully updated),
            // overlapping the other waves' update work until the barrier.
            // if/else keeps the acc[] index compile-time static (no scratch).
            if (w == ((c + 1) >> 1)) {
                if ((c + 1) & 1) scan_chunk(c + 1, acc[1]);
                else             scan_chunk(c + 1, acc[0]);
            }
            Acur0 = Anext0;
            Acur1 = Anext1;
        }
        __syncthreads();
    }
}

extern "C" void kernel_launch(void* const* d_in, const int* in_sizes, int n_in,
                              void* d_out, int out_size, void* d_ws, size_t ws_size,
                              hipStream_t stream)
{
    const float* X   = (const float*)d_in[0];
    const float* Wi  = (const float*)d_in[1];
    const int*   obs = (const int*)d_in[2];
    float*       out = (float*)d_out;

    float*          Gd = (float*)d_ws;                                  //  1 MB
    float*          P0 = (float*)((char*)d_ws + (1u << 20));            //  8 MB
    unsigned short* Gh = (unsigned short*)((char*)d_ws + (9u << 20));   //  8 MB

    hipLaunchKernelGGL(k1_gemm, dim3(NB * 5), dim3(256), 0, stream,
                       X, Wi, obs, Gd, Gh, P0);
    hipLaunchKernelGGL(k2_scan, dim3(NB * 8), dim3(512), 0, stream,
                       Gd, Gh, P0, out);
}